// Round 4
// baseline (73.491 us; speedup 1.0000x reference)
//
#include <hip/hip_runtime.h>
#include <hip/hip_bf16.h>

#define N_PAIR 4096
#define N_ROW  8192
#define DIM    128
#define NX     4     // col-tiles swept per block

typedef __attribute__((ext_vector_type(4))) float   f32x4;
typedef __bf16 bf16x8 __attribute__((ext_vector_type(8)));

__device__ inline unsigned short f2bf(float x) {
    union { float f; unsigned int u; } c; c.f = x;
    unsigned int u = c.u;
    return (unsigned short)((u + 0x7fffu + ((u >> 16) & 1u)) >> 16);
}

// K1: fused interleave + L2-normalize -> zh (bf16 [8192][128]); partner dot -> pd;
//     zero rowsum. One pair (rows 2k, 2k+1) per wave.
__global__ __launch_bounds__(256) void k_prep(const float* __restrict__ zi,
                                              const float* __restrict__ zj,
                                              unsigned short* __restrict__ zh,
                                              float* __restrict__ pd,
                                              float* __restrict__ rowsum) {
    const int wid  = threadIdx.x >> 6;
    const int lane = threadIdx.x & 63;
    const int k    = blockIdx.x * 4 + wid;          // pair 0..4095
    float2 a = *(const float2*)&zi[k * DIM + lane * 2];
    float2 b = *(const float2*)&zj[k * DIM + lane * 2];
    float ssi = a.x * a.x + a.y * a.y;
    float ssj = b.x * b.x + b.y * b.y;
    float dot = a.x * b.x + a.y * b.y;
#pragma unroll
    for (int off = 1; off < 64; off <<= 1) {
        ssi += __shfl_xor(ssi, off);
        ssj += __shfl_xor(ssj, off);
        dot += __shfl_xor(dot, off);
    }
    const float invi = rsqrtf(ssi), invj = rsqrtf(ssj);
    unsigned int wi = ((unsigned int)f2bf(a.y * invi) << 16) | f2bf(a.x * invi);
    unsigned int wj = ((unsigned int)f2bf(b.y * invj) << 16) | f2bf(b.x * invj);
    ((unsigned int*)zh)[(2 * k)     * (DIM / 2) + lane] = wi;
    ((unsigned int*)zh)[(2 * k + 1) * (DIM / 2) + lane] = wj;
    if (lane == 0) {
        pd[k] = dot * invi * invj;
        rowsum[2 * k]     = 0.f;
        rowsum[2 * k + 1] = 0.f;
    }
}

// K2: full-matrix S = Zh*Zh^T, TRANSPOSED mfma (accT[n][m] = mfma(b,a)) so each
//     output ROW lives in one lane -> rowsum of exp() is lane-local FMA.
//     Each block sweeps NX col-tiles with rowsum carried in registers; one
//     shuffle-pair + 4 atomics per wave at the very end.
__global__ __launch_bounds__(256) void k_simsum(const unsigned short* __restrict__ zh,
                                                float* __restrict__ rowsum) {
    const int tid  = threadIdx.x;
    const int lane = tid & 63;
    const int wid  = tid >> 6;
    const int wr   = wid >> 1, wc = wid & 1;
    const int l15  = lane & 15, lhi = lane >> 4;
    const int by   = blockIdx.y;
    const int row0 = by * 128 + wr * 64;            // wave's A-row base

    const float K2E = 2.8853900817779268f;          // 2/ln2: exp(2s) = exp2(K2E*s)
    float rs[4] = {0.f, 0.f, 0.f, 0.f};             // rowsum partial, row = row0+m*16+l15

#pragma unroll 1
    for (int t = 0; t < NX; ++t) {
        const int bx   = blockIdx.x * NX + t;
        const int col0 = bx * 128 + wc * 64;        // wave's B-row (=S-col) base
        f32x4 accT[4][4] = {};                      // accT[n][m]: reg r -> col, l15 -> row
#pragma unroll
        for (int kk = 0; kk < 4; ++kk) {
            bf16x8 a[4], b[4];
#pragma unroll
            for (int m = 0; m < 4; ++m)
                a[m] = *(const bf16x8*)&zh[(row0 + m * 16 + l15) * DIM + kk * 32 + lhi * 8];
#pragma unroll
            for (int n = 0; n < 4; ++n)
                b[n] = *(const bf16x8*)&zh[(col0 + n * 16 + l15) * DIM + kk * 32 + lhi * 8];
#pragma unroll
            for (int n = 0; n < 4; ++n)
#pragma unroll
                for (int m = 0; m < 4; ++m)
                    accT[n][m] = __builtin_amdgcn_mfma_f32_16x16x32_bf16(b[n], a[m], accT[n][m], 0, 0, 0);
        }
        if (bx == by) {
            // diagonal tile: zero elements where global col == global row
#pragma unroll
            for (int m = 0; m < 4; ++m) {
                const int rloc = wr * 64 + m * 16 + l15;   // row within 128-tile
                float s0 = 0.f, s1 = 0.f;
#pragma unroll
                for (int n = 0; n < 4; ++n)
#pragma unroll
                    for (int r = 0; r < 4; ++r) {
                        const int cloc = wc * 64 + n * 16 + lhi * 4 + r;
                        float v = exp2f(K2E * accT[n][m][r]);
                        v = (cloc == rloc) ? 0.f : v;
                        if (n < 2) s0 += v; else s1 += v;
                    }
                rs[m] += s0 + s1;
            }
        } else {
#pragma unroll
            for (int m = 0; m < 4; ++m) {
                float s0 = 0.f, s1 = 0.f;
#pragma unroll
                for (int n = 0; n < 4; ++n)
#pragma unroll
                    for (int r = 0; r < 4; ++r) {
                        float v = exp2f(K2E * accT[n][m][r]);
                        if (n < 2) s0 += v; else s1 += v;
                    }
                rs[m] += s0 + s1;
            }
        }
    }
    // reduce over lhi groups (rows are per-l15); then 4 atomics per wave
#pragma unroll
    for (int m = 0; m < 4; ++m) {
        rs[m] += __shfl_xor(rs[m], 16);
        rs[m] += __shfl_xor(rs[m], 32);
    }
    if (lane < 16) {
#pragma unroll
        for (int m = 0; m < 4; ++m)
            atomicAdd(&rowsum[row0 + m * 16 + lane], rs[m]);
    }
}

// K3: loss partials: each of 32 blocks covers 256 rows; pre-divided float atomic.
__global__ __launch_bounds__(256) void k_loss(const float* __restrict__ rowsum,
                                              const float* __restrict__ pd,
                                              float* __restrict__ out) {
    const int tid  = threadIdx.x;
    const int lane = tid & 63;
    const int wid  = tid >> 6;
    const int i    = blockIdx.x * 256 + tid;        // 0..8191
    const float LN2 = 0.6931471805599453f;
    float local = log2f(rowsum[i]) * LN2 - 2.f * pd[i >> 1];
#pragma unroll
    for (int off = 1; off < 64; off <<= 1) local += __shfl_xor(local, off);
    __shared__ float wsum[4];
    if (lane == 0) wsum[wid] = local;
    __syncthreads();
    if (tid == 0)
        atomicAdd(out, (wsum[0] + wsum[1] + wsum[2] + wsum[3]) * (1.f / (float)N_ROW));
}

extern "C" void kernel_launch(void* const* d_in, const int* in_sizes, int n_in,
                              void* d_out, int out_size, void* d_ws, size_t ws_size,
                              hipStream_t stream) {
    const float* zi = (const float*)d_in[0];
    const float* zj = (const float*)d_in[1];
    char* ws = (char*)d_ws;
    unsigned short* zh = (unsigned short*)ws;                     // 2 MiB
    float* rowsum = (float*)(ws + 2 * 1024 * 1024);               // 32 KiB
    float* pd     = (float*)(ws + 2 * 1024 * 1024 + 32 * 1024);   // 16 KiB

    hipMemsetAsync(d_out, 0, sizeof(float), stream);
    k_prep<<<N_PAIR / 4, 256, 0, stream>>>(zi, zj, zh, pd, rowsum);
    dim3 grid(64 / NX, 64);
    k_simsum<<<grid, 256, 0, stream>>>(zh, rowsum);
    k_loss<<<N_ROW / 256, 256, 0, stream>>>(rowsum, pd, (float*)d_out);
}

// Round 5
// 48.623 us; speedup vs baseline: 1.5115x; 1.5115x over previous
//
#include <hip/hip_runtime.h>
#include <hip/hip_bf16.h>

#define N_PAIR 4096
#define N_ROW  8192
#define DIM    128
#define NX     8     // col-tiles swept per block

typedef __attribute__((ext_vector_type(4))) float   f32x4;
typedef __bf16 bf16x8 __attribute__((ext_vector_type(8)));

__device__ inline unsigned short f2bf(float x) {
    union { float f; unsigned int u; } c; c.f = x;
    unsigned int u = c.u;
    return (unsigned short)((u + 0x7fffu + ((u >> 16) & 1u)) >> 16);
}

// K1: fused interleave + L2-normalize -> zh (bf16 [8192][128]); partner dot -> pd;
//     zero rowsum. One pair (rows 2k, 2k+1) per wave.
__global__ __launch_bounds__(256) void k_prep(const float* __restrict__ zi,
                                              const float* __restrict__ zj,
                                              unsigned short* __restrict__ zh,
                                              float* __restrict__ pd,
                                              float* __restrict__ rowsum) {
    const int wid  = threadIdx.x >> 6;
    const int lane = threadIdx.x & 63;
    const int k    = blockIdx.x * 4 + wid;          // pair 0..4095
    float2 a = *(const float2*)&zi[k * DIM + lane * 2];
    float2 b = *(const float2*)&zj[k * DIM + lane * 2];
    float ssi = a.x * a.x + a.y * a.y;
    float ssj = b.x * b.x + b.y * b.y;
    float dot = a.x * b.x + a.y * b.y;
#pragma unroll
    for (int off = 1; off < 64; off <<= 1) {
        ssi += __shfl_xor(ssi, off);
        ssj += __shfl_xor(ssj, off);
        dot += __shfl_xor(dot, off);
    }
    const float invi = rsqrtf(ssi), invj = rsqrtf(ssj);
    unsigned int wi = ((unsigned int)f2bf(a.y * invi) << 16) | f2bf(a.x * invi);
    unsigned int wj = ((unsigned int)f2bf(b.y * invj) << 16) | f2bf(b.x * invj);
    ((unsigned int*)zh)[(2 * k)     * (DIM / 2) + lane] = wi;
    ((unsigned int*)zh)[(2 * k + 1) * (DIM / 2) + lane] = wj;
    if (lane == 0) {
        pd[k] = dot * invi * invj;
        rowsum[2 * k]     = 0.f;
        rowsum[2 * k + 1] = 0.f;
    }
}

// K2: full-matrix S = Zh*Zh^T. Per block: 128-row strip (A-frags hoisted to
//     registers, t-invariant) x NX col-tiles. B double-buffered in LDS via
//     global_load_lds w16 (linear dest + inverse-swizzled source, XOR-swizzled
//     ds_read). Transposed mfma(b,a) -> output row lane-local -> rowsum is
//     register FMA; 2 shuffles + 4 atomics per wave at the end.
__global__ __launch_bounds__(256, 2) void k_simsum(const unsigned short* __restrict__ zh,
                                                   float* __restrict__ rowsum) {
    __shared__ unsigned short Bs[2][16384];         // 2 x 32 KB (128 rows x 256B)
    const int tid  = threadIdx.x;
    const int lane = tid & 63;
    const int wid  = tid >> 6;
    const int wr   = wid >> 1, wc = wid & 1;
    const int l15  = lane & 15, lhi = lane >> 4;
    const int by   = blockIdx.y;
    const int bx0  = blockIdx.x * NX;
    const int row0 = by * 128 + wr * 64;            // wave's A-row base

    // A fragments, invariant across the col-tile sweep: a[kk][m]
    bf16x8 a[4][4];
#pragma unroll
    for (int kk = 0; kk < 4; ++kk)
#pragma unroll
        for (int m = 0; m < 4; ++m)
            a[kk][m] = *(const bf16x8*)&zh[(row0 + m * 16 + l15) * DIM + kk * 32 + lhi * 8];

    // stage col-tile ct into Bs[buf]: LDS linear, global source pre-swizzled
    // (chunk16 g = b16 ^ (row&7)); ds_read applies the same XOR (involution).
    const int r4  = lane >> 4;                      // row within 4-row chunk
    const int b16 = lane & 15;                      // 16B slot within row
    auto stage = [&](int ct, int buf) {
#pragma unroll
        for (int i = 0; i < 8; ++i) {
            const int chunk = wid * 8 + i;          // 0..31 (1 KB each)
            const int r = chunk * 4 + r4;           // 0..127
            const int g = b16 ^ (r & 7);
            const unsigned short* src = zh + (ct * 128 + r) * DIM + g * 8;
            __builtin_amdgcn_global_load_lds(
                (const __attribute__((address_space(1))) void*)src,
                (__attribute__((address_space(3))) void*)(&Bs[buf][chunk * 512]),
                16, 0, 0);
        }
    };

    const float K2E = 2.8853900817779268f;          // 2/ln2: exp(2s)=exp2(K2E*s)
    float rs[4] = {0.f, 0.f, 0.f, 0.f};

    stage(bx0, 0);
    asm volatile("s_waitcnt vmcnt(0)" ::: "memory");
    __builtin_amdgcn_s_barrier();

    int cur = 0;
#pragma unroll 1
    for (int t = 0; t < NX; ++t) {
        if (t + 1 < NX) stage(bx0 + t + 1, cur ^ 1);   // prefetch next tile
        const int bx = bx0 + t;
        f32x4 accT[4][4] = {};                      // [n][m]: reg->col, l15->row
#pragma unroll
        for (int kk = 0; kk < 4; ++kk) {
            bf16x8 b[4];
#pragma unroll
            for (int n = 0; n < 4; ++n) {
                const int row = wc * 64 + n * 16 + l15;
                const int c   = (kk * 4 + lhi) ^ (l15 & 7);
                b[n] = *(const bf16x8*)&Bs[cur][row * 128 + c * 8];
            }
#pragma unroll
            for (int n = 0; n < 4; ++n)
#pragma unroll
                for (int m = 0; m < 4; ++m)
                    accT[n][m] = __builtin_amdgcn_mfma_f32_16x16x32_bf16(b[n], a[kk][m], accT[n][m], 0, 0, 0);
        }
        if (bx == by) {                              // diagonal tile: mask col==row
#pragma unroll
            for (int m = 0; m < 4; ++m) {
                const int rloc = wr * 64 + m * 16 + l15;
                float s0 = 0.f, s1 = 0.f;
#pragma unroll
                for (int n = 0; n < 4; ++n)
#pragma unroll
                    for (int r = 0; r < 4; ++r) {
                        const int cloc = wc * 64 + n * 16 + lhi * 4 + r;
                        float v = exp2f(K2E * accT[n][m][r]);
                        v = (cloc == rloc) ? 0.f : v;
                        if (n < 2) s0 += v; else s1 += v;
                    }
                rs[m] += s0 + s1;
            }
        } else {
#pragma unroll
            for (int m = 0; m < 4; ++m) {
                float s0 = 0.f, s1 = 0.f;
#pragma unroll
                for (int n = 0; n < 4; ++n)
#pragma unroll
                    for (int r = 0; r < 4; ++r) {
                        float v = exp2f(K2E * accT[n][m][r]);
                        if (n < 2) s0 += v; else s1 += v;
                    }
                rs[m] += s0 + s1;
            }
        }
        asm volatile("s_waitcnt vmcnt(0)" ::: "memory");   // next tile staged
        __builtin_amdgcn_s_barrier();                      // + all reads of cur done
        cur ^= 1;
    }

    // rows are per-l15; fold the 4 lhi groups, then 4 atomics per wave
#pragma unroll
    for (int m = 0; m < 4; ++m) {
        rs[m] += __shfl_xor(rs[m], 16);
        rs[m] += __shfl_xor(rs[m], 32);
    }
    if (lane < 16) {
#pragma unroll
        for (int m = 0; m < 4; ++m)
            atomicAdd(&rowsum[row0 + m * 16 + lane], rs[m]);
    }
}

// K3: loss partials: each of 32 blocks covers 256 rows; pre-divided float atomic.
__global__ __launch_bounds__(256) void k_loss(const float* __restrict__ rowsum,
                                              const float* __restrict__ pd,
                                              float* __restrict__ out) {
    const int tid  = threadIdx.x;
    const int lane = tid & 63;
    const int wid  = tid >> 6;
    const int i    = blockIdx.x * 256 + tid;        // 0..8191
    const float LN2 = 0.6931471805599453f;
    float local = log2f(rowsum[i]) * LN2 - 2.f * pd[i >> 1];
#pragma unroll
    for (int off = 1; off < 64; off <<= 1) local += __shfl_xor(local, off);
    __shared__ float wsum[4];
    if (lane == 0) wsum[wid] = local;
    __syncthreads();
    if (tid == 0)
        atomicAdd(out, (wsum[0] + wsum[1] + wsum[2] + wsum[3]) * (1.f / (float)N_ROW));
}

extern "C" void kernel_launch(void* const* d_in, const int* in_sizes, int n_in,
                              void* d_out, int out_size, void* d_ws, size_t ws_size,
                              hipStream_t stream) {
    const float* zi = (const float*)d_in[0];
    const float* zj = (const float*)d_in[1];
    char* ws = (char*)d_ws;
    unsigned short* zh = (unsigned short*)ws;                     // 2 MiB
    float* rowsum = (float*)(ws + 2 * 1024 * 1024);               // 32 KiB
    float* pd     = (float*)(ws + 2 * 1024 * 1024 + 32 * 1024);   // 16 KiB

    hipMemsetAsync(d_out, 0, sizeof(float), stream);
    k_prep<<<N_PAIR / 4, 256, 0, stream>>>(zi, zj, zh, pd, rowsum);
    dim3 grid(64 / NX, 64);
    k_simsum<<<grid, 256, 0, stream>>>(zh, rowsum);
    k_loss<<<N_ROW / 256, 256, 0, stream>>>(rowsum, pd, (float*)d_out);
}

// Round 6
// 38.228 us; speedup vs baseline: 1.9224x; 1.2719x over previous
//
#include <hip/hip_runtime.h>
#include <hip/hip_bf16.h>

#define N_PAIR 4096
#define N_ROW  8192
#define DIM    128
#define NX     8     // col-tiles swept per block

typedef __attribute__((ext_vector_type(4))) float   f32x4;
typedef __bf16 bf16x8 __attribute__((ext_vector_type(8)));

__device__ inline unsigned short f2bf(float x) {
    union { float f; unsigned int u; } c; c.f = x;
    unsigned int u = c.u;
    return (unsigned short)((u + 0x7fffu + ((u >> 16) & 1u)) >> 16);
}

// raw v_exp_f32: inputs bounded to [-2.9, 2.9] here, no denorm/overflow concerns
__device__ inline float fast_exp2(float x) {
#if __has_builtin(__builtin_amdgcn_exp2f)
    return __builtin_amdgcn_exp2f(x);
#else
    float r; asm("v_exp_f32 %0, %1" : "=v"(r) : "v"(x)); return r;
#endif
}
// raw v_log_f32 (= log2)
__device__ inline float fast_log2(float x) {
#if __has_builtin(__builtin_amdgcn_logf)
    return __builtin_amdgcn_logf(x);
#else
    float r; asm("v_log_f32 %0, %1" : "=v"(r) : "v"(x)); return r;
#endif
}

// K1: fused interleave + L2-normalize -> zh (bf16 [8192][128]); partner dot -> pd;
//     zero rowsum. One pair (rows 2k, 2k+1) per wave.
__global__ __launch_bounds__(256) void k_prep(const float* __restrict__ zi,
                                              const float* __restrict__ zj,
                                              unsigned short* __restrict__ zh,
                                              float* __restrict__ pd,
                                              float* __restrict__ rowsum) {
    const int wid  = threadIdx.x >> 6;
    const int lane = threadIdx.x & 63;
    const int k    = blockIdx.x * 4 + wid;          // pair 0..4095
    float2 a = *(const float2*)&zi[k * DIM + lane * 2];
    float2 b = *(const float2*)&zj[k * DIM + lane * 2];
    float ssi = a.x * a.x + a.y * a.y;
    float ssj = b.x * b.x + b.y * b.y;
    float dot = a.x * b.x + a.y * b.y;
#pragma unroll
    for (int off = 1; off < 64; off <<= 1) {
        ssi += __shfl_xor(ssi, off);
        ssj += __shfl_xor(ssj, off);
        dot += __shfl_xor(dot, off);
    }
    const float invi = rsqrtf(ssi), invj = rsqrtf(ssj);
    unsigned int wi = ((unsigned int)f2bf(a.y * invi) << 16) | f2bf(a.x * invi);
    unsigned int wj = ((unsigned int)f2bf(b.y * invj) << 16) | f2bf(b.x * invj);
    ((unsigned int*)zh)[(2 * k)     * (DIM / 2) + lane] = wi;
    ((unsigned int*)zh)[(2 * k + 1) * (DIM / 2) + lane] = wj;
    if (lane == 0) {
        pd[k] = dot * invi * invj;
        rowsum[2 * k]     = 0.f;
        rowsum[2 * k + 1] = 0.f;
    }
}

// K2: full-matrix S = Zh*Zh^T. Per block: 128-row strip (A-frags hoisted to
//     registers, t-invariant) x NX col-tiles. B double-buffered in LDS via
//     global_load_lds w16 (linear dest + inverse-swizzled source, XOR-swizzled
//     ds_read). Transposed mfma(b,a) -> output row lane-local -> rowsum is
//     register FMA; 2 shuffles + 4 atomics per wave at the end.
__global__ __launch_bounds__(256, 2) void k_simsum(const unsigned short* __restrict__ zh,
                                                   float* __restrict__ rowsum) {
    __shared__ unsigned short Bs[2][16384];         // 2 x 32 KB (128 rows x 256B)
    const int tid  = threadIdx.x;
    const int lane = tid & 63;
    const int wid  = tid >> 6;
    const int wr   = wid >> 1, wc = wid & 1;
    const int l15  = lane & 15, lhi = lane >> 4;
    const int by   = blockIdx.y;
    const int bx0  = blockIdx.x * NX;
    const int row0 = by * 128 + wr * 64;            // wave's A-row base

    // A fragments, invariant across the col-tile sweep: a[kk][m]
    bf16x8 a[4][4];
#pragma unroll
    for (int kk = 0; kk < 4; ++kk)
#pragma unroll
        for (int m = 0; m < 4; ++m)
            a[kk][m] = *(const bf16x8*)&zh[(row0 + m * 16 + l15) * DIM + kk * 32 + lhi * 8];

    // stage col-tile ct into Bs[buf]: LDS linear, global source pre-swizzled
    // (chunk16 g = b16 ^ (row&7)); ds_read applies the same XOR (involution).
    const int r4  = lane >> 4;                      // row within 4-row chunk
    const int b16 = lane & 15;                      // 16B slot within row
    auto stage = [&](int ct, int buf) {
#pragma unroll
        for (int i = 0; i < 8; ++i) {
            const int chunk = wid * 8 + i;          // 0..31 (1 KB each)
            const int r = chunk * 4 + r4;           // 0..127
            const int g = b16 ^ (r & 7);
            const unsigned short* src = zh + (ct * 128 + r) * DIM + g * 8;
            __builtin_amdgcn_global_load_lds(
                (const __attribute__((address_space(1))) void*)src,
                (__attribute__((address_space(3))) void*)(&Bs[buf][chunk * 512]),
                16, 0, 0);
        }
    };

    const float K2E = 2.8853900817779268f;          // 2/ln2: exp(2s)=exp2(K2E*s)
    float rs[4] = {0.f, 0.f, 0.f, 0.f};

    stage(bx0, 0);
    asm volatile("s_waitcnt vmcnt(0)" ::: "memory");
    __builtin_amdgcn_s_barrier();

    int cur = 0;
#pragma unroll 1
    for (int t = 0; t < NX; ++t) {
        if (t + 1 < NX) stage(bx0 + t + 1, cur ^ 1);   // prefetch next tile
        const int bx = bx0 + t;
        f32x4 accT[4][4] = {};                      // [n][m]: reg->col, l15->row
#pragma unroll
        for (int kk = 0; kk < 4; ++kk) {
            bf16x8 b[4];
#pragma unroll
            for (int n = 0; n < 4; ++n) {
                const int row = wc * 64 + n * 16 + l15;
                const int c   = (kk * 4 + lhi) ^ (l15 & 7);
                b[n] = *(const bf16x8*)&Bs[cur][row * 128 + c * 8];
            }
#pragma unroll
            for (int n = 0; n < 4; ++n)
#pragma unroll
                for (int m = 0; m < 4; ++m)
                    accT[n][m] = __builtin_amdgcn_mfma_f32_16x16x32_bf16(b[n], a[kk][m], accT[n][m], 0, 0, 0);
        }
        if (bx == by) {                              // diagonal tile: mask col==row
#pragma unroll
            for (int m = 0; m < 4; ++m) {
                const int rloc = wr * 64 + m * 16 + l15;
                float s0 = 0.f, s1 = 0.f;
#pragma unroll
                for (int n = 0; n < 4; ++n)
#pragma unroll
                    for (int r = 0; r < 4; ++r) {
                        const int cloc = wc * 64 + n * 16 + lhi * 4 + r;
                        float v = fast_exp2(K2E * accT[n][m][r]);
                        v = (cloc == rloc) ? 0.f : v;
                        if (n < 2) s0 += v; else s1 += v;
                    }
                rs[m] += s0 + s1;
            }
        } else {
#pragma unroll
            for (int m = 0; m < 4; ++m) {
                float s0 = 0.f, s1 = 0.f;
#pragma unroll
                for (int n = 0; n < 4; ++n)
#pragma unroll
                    for (int r = 0; r < 4; ++r) {
                        float v = fast_exp2(K2E * accT[n][m][r]);
                        if (n < 2) s0 += v; else s1 += v;
                    }
                rs[m] += s0 + s1;
            }
        }
        asm volatile("s_waitcnt vmcnt(0)" ::: "memory");   // next tile staged
        __builtin_amdgcn_s_barrier();                      // + all reads of cur done
        cur ^= 1;
    }

    // rows are per-l15; fold the 4 lhi groups, then 4 atomics per wave
#pragma unroll
    for (int m = 0; m < 4; ++m) {
        rs[m] += __shfl_xor(rs[m], 16);
        rs[m] += __shfl_xor(rs[m], 32);
    }
    if (lane < 16) {
#pragma unroll
        for (int m = 0; m < 4; ++m)
            atomicAdd(&rowsum[row0 + m * 16 + lane], rs[m]);
    }
}

// K3: loss partials: each of 32 blocks covers 256 rows; pre-divided float atomic.
__global__ __launch_bounds__(256) void k_loss(const float* __restrict__ rowsum,
                                              const float* __restrict__ pd,
                                              float* __restrict__ out) {
    const int tid  = threadIdx.x;
    const int lane = tid & 63;
    const int wid  = tid >> 6;
    const int i    = blockIdx.x * 256 + tid;        // 0..8191
    const float LN2 = 0.6931471805599453f;
    float local = fast_log2(rowsum[i]) * LN2 - 2.f * pd[i >> 1];
#pragma unroll
    for (int off = 1; off < 64; off <<= 1) local += __shfl_xor(local, off);
    __shared__ float wsum[4];
    if (lane == 0) wsum[wid] = local;
    __syncthreads();
    if (tid == 0)
        atomicAdd(out, (wsum[0] + wsum[1] + wsum[2] + wsum[3]) * (1.f / (float)N_ROW));
}

extern "C" void kernel_launch(void* const* d_in, const int* in_sizes, int n_in,
                              void* d_out, int out_size, void* d_ws, size_t ws_size,
                              hipStream_t stream) {
    const float* zi = (const float*)d_in[0];
    const float* zj = (const float*)d_in[1];
    char* ws = (char*)d_ws;
    unsigned short* zh = (unsigned short*)ws;                     // 2 MiB
    float* rowsum = (float*)(ws + 2 * 1024 * 1024);               // 32 KiB
    float* pd     = (float*)(ws + 2 * 1024 * 1024 + 32 * 1024);   // 16 KiB

    hipMemsetAsync(d_out, 0, sizeof(float), stream);
    k_prep<<<N_PAIR / 4, 256, 0, stream>>>(zi, zj, zh, pd, rowsum);
    dim3 grid(64 / NX, 64);
    k_simsum<<<grid, 256, 0, stream>>>(zh, rowsum);
    k_loss<<<N_ROW / 256, 256, 0, stream>>>(rowsum, pd, (float*)d_out);
}